// Round 4
// baseline (1509.040 us; speedup 1.0000x reference)
//
#include <hip/hip_runtime.h>
#include <hip/hip_bf16.h>

typedef __attribute__((ext_vector_type(8))) short short8;   // bf16x8 frag (4 VGPR)
typedef __attribute__((ext_vector_type(4))) float floatx4;  // mfma acc / fp32 vec
typedef __attribute__((ext_vector_type(4))) int intx4;
typedef __attribute__((ext_vector_type(4))) unsigned short ushortx4;

#define NB 4
#define EPS 1e-5f

static __device__ __forceinline__ float bf2f(unsigned short h) {
  unsigned int u = ((unsigned int)h) << 16;
  return __builtin_bit_cast(float, u);
}
static __device__ __forceinline__ unsigned short f2bf(float f) {
  unsigned int u = __builtin_bit_cast(unsigned int, f);
  u += 0x7fffu + ((u >> 16) & 1u);
  return (unsigned short)(u >> 16);
}

// Swizzle fp32 W [batch][Kdim][Ncols] into bf16 MFMA B-fragment order:
// frag (b,s,t): lane l holds B[s*32 + (l>>4)*8 + j][t*16 + (l&15)], j=0..7.
__global__ void swizzle_w(const float* __restrict__ W,
                          unsigned short* __restrict__ out,
                          int Kdim, int Ncols, int batch) {
  int S = Kdim >> 5, T = Ncols >> 4;
  int total = batch * S * T * 64;
  int gid = blockIdx.x * blockDim.x + threadIdx.x;
  if (gid >= total) return;
  int l = gid & 63;
  int rest = gid >> 6;
  int t = rest % T; rest /= T;
  int s = rest % S; int b = rest / S;
  const float* Wb = W + (size_t)b * Kdim * Ncols;
  unsigned short* ob = out + (size_t)gid * 8;
  int kbase = s * 32 + (l >> 4) * 8;
  int n = t * 16 + (l & 15);
#pragma unroll
  for (int j = 0; j < 8; ++j) ob[j] = f2bf(Wb[(size_t)(kbase + j) * Ncols + n]);
}

// h1 (bf16, pre-norm) = feats[N,256](fp32) @ W1. Wave = 16 rows x 64 cols.
__launch_bounds__(256)
__global__ void gemm1(const float* __restrict__ feats,
                      const unsigned short* __restrict__ w1s,
                      unsigned short* __restrict__ h1, int N) {
  int wave = threadIdx.x >> 6;
  int l = threadIdx.x & 63;
  int r0 = blockIdx.x * 64 + wave * 16;
  const float* arow = feats + (size_t)(r0 + (l & 15)) * 256 + (l >> 4) * 8;
  floatx4 acc[4];
#pragma unroll
  for (int t = 0; t < 4; ++t) acc[t] = (floatx4){0.f, 0.f, 0.f, 0.f};
#pragma unroll
  for (int s = 0; s < 8; ++s) {
    floatx4 f0 = *(const floatx4*)(arow + s * 32);
    floatx4 f1 = *(const floatx4*)(arow + s * 32 + 4);
    short8 a;
#pragma unroll
    for (int j = 0; j < 4; ++j) { a[j] = (short)f2bf(f0[j]); a[j + 4] = (short)f2bf(f1[j]); }
#pragma unroll
    for (int t = 0; t < 4; ++t) {
      short8 b = *(const short8*)(w1s + ((size_t)(s * 4 + t) * 64 + l) * 8);
      acc[t] = __builtin_amdgcn_mfma_f32_16x16x32_bf16(a, b, acc[t], 0, 0, 0);
    }
  }
  int col0 = l & 15;
#pragma unroll
  for (int t = 0; t < 4; ++t)
#pragma unroll
    for (int reg = 0; reg < 4; ++reg) {
      int r = r0 + (l >> 4) * 4 + reg;
      h1[(size_t)r * 64 + t * 16 + col0] = f2bf(acc[t][reg]);
    }
}

// per-(instance,channel) sum/sumsq over bf16 [N,64] + row counts
__global__ void stats64_bf(const unsigned short* __restrict__ x,
                           const int* __restrict__ batch_idx,
                           float* __restrict__ sum, float* __restrict__ sq,
                           float* __restrict__ cnt, int N) {
  int c = threadIdx.x & 63;
  int rg = threadIdx.x >> 6;
  float s0 = 0, s1 = 0, s2 = 0, s3 = 0, q0 = 0, q1 = 0, q2 = 0, q3 = 0;
  float c0 = 0, c1 = 0, c2 = 0, c3 = 0;
  for (int i = blockIdx.x * 4 + rg; i < N; i += gridDim.x * 4) {
    int b = batch_idx[i];
    float v = bf2f(x[(size_t)i * 64 + c]);
    float v2 = v * v;
    if (b == 0) { s0 += v; q0 += v2; c0 += 1.f; }
    else if (b == 1) { s1 += v; q1 += v2; c1 += 1.f; }
    else if (b == 2) { s2 += v; q2 += v2; c2 += 1.f; }
    else { s3 += v; q3 += v2; c3 += 1.f; }
  }
  atomicAdd(&sum[0 * 64 + c], s0); atomicAdd(&sq[0 * 64 + c], q0);
  atomicAdd(&sum[1 * 64 + c], s1); atomicAdd(&sq[1 * 64 + c], q1);
  atomicAdd(&sum[2 * 64 + c], s2); atomicAdd(&sq[2 * 64 + c], q2);
  atomicAdd(&sum[3 * 64 + c], s3); atomicAdd(&sq[3 * 64 + c], q3);
  if (c == 0) {
    atomicAdd(&cnt[0], c0); atomicAdd(&cnt[1], c1);
    atomicAdd(&cnt[2], c2); atomicAdd(&cnt[3], c3);
  }
}

// per-(instance,channel) sum/sumsq over fp32 [N,64]
__global__ void stats64_f32(const float* __restrict__ x,
                            const int* __restrict__ batch_idx,
                            float* __restrict__ sum, float* __restrict__ sq, int N) {
  int c = threadIdx.x & 63;
  int rg = threadIdx.x >> 6;
  float s0 = 0, s1 = 0, s2 = 0, s3 = 0, q0 = 0, q1 = 0, q2 = 0, q3 = 0;
  for (int i = blockIdx.x * 4 + rg; i < N; i += gridDim.x * 4) {
    int b = batch_idx[i];
    float v = x[(size_t)i * 64 + c];
    float v2 = v * v;
    if (b == 0) { s0 += v; q0 += v2; }
    else if (b == 1) { s1 += v; q1 += v2; }
    else if (b == 2) { s2 += v; q2 += v2; }
    else { s3 += v; q3 += v2; }
  }
  atomicAdd(&sum[0 * 64 + c], s0); atomicAdd(&sq[0 * 64 + c], q0);
  atomicAdd(&sum[1 * 64 + c], s1); atomicAdd(&sq[1 * 64 + c], q1);
  atomicAdd(&sum[2 * 64 + c], s2); atomicAdd(&sq[2 * 64 + c], q2);
  atomicAdd(&sum[3 * 64 + c], s3); atomicAdd(&sq[3 * 64 + c], q3);
}

// per-(instance,channel) sum/sumsq over fp32 [N,256]
__global__ void stats256_f32(const float* __restrict__ y,
                             const int* __restrict__ batch_idx,
                             float* __restrict__ sum, float* __restrict__ sq, int N) {
  int c = threadIdx.x;  // 256 threads
  float s0 = 0, s1 = 0, s2 = 0, s3 = 0, q0 = 0, q1 = 0, q2 = 0, q3 = 0;
  for (int i = blockIdx.x; i < N; i += gridDim.x) {
    int b = batch_idx[i];
    float v = y[(size_t)i * 256 + c];
    float v2 = v * v;
    if (b == 0) { s0 += v; q0 += v2; }
    else if (b == 1) { s1 += v; q1 += v2; }
    else if (b == 2) { s2 += v; q2 += v2; }
    else { s3 += v; q3 += v2; }
  }
  atomicAdd(&sum[0 * 256 + c], s0); atomicAdd(&sq[0 * 256 + c], q0);
  atomicAdd(&sum[1 * 256 + c], s1); atomicAdd(&sq[1 * 256 + c], q1);
  atomicAdd(&sum[2 * 256 + c], s2); atomicAdd(&sq[2 * 256 + c], q2);
  atomicAdd(&sum[3 * 256 + c], s3); atomicAdd(&sq[3 * 256 + c], q3);
}

__global__ void finalize_stats(const float* __restrict__ sum, const float* __restrict__ sq,
                               const float* __restrict__ cnt, float* __restrict__ mean,
                               float* __restrict__ inv, int C) {
  int i = blockIdx.x * blockDim.x + threadIdx.x;
  if (i >= NB * C) return;
  int b = i / C;
  float n = cnt[b];
  float m = sum[i] / n;
  float v = sq[i] / n - m * m;
  mean[i] = m;
  inv[i] = rsqrtf(v + EPS);
}

// in-place: x = relu((x - mean)*inv), bf16 [N,64]
__global__ void norm64_bf_inplace(unsigned short* __restrict__ x,
                                  const int* __restrict__ batch_idx,
                                  const float* __restrict__ mean,
                                  const float* __restrict__ inv, int N) {
  size_t total = (size_t)N * 16;  // N*64/4
  for (size_t i = (size_t)blockIdx.x * blockDim.x + threadIdx.x; i < total;
       i += (size_t)gridDim.x * blockDim.x) {
    size_t e = i * 4;
    int row = (int)(e >> 6);
    int c = (int)(e & 63);
    int b = batch_idx[row];
    ushortx4 v = *(const ushortx4*)(x + e);
    ushortx4 o;
#pragma unroll
    for (int j = 0; j < 4; ++j) {
      float t = (bf2f(v[j]) - mean[b * 64 + c + j]) * inv[b * 64 + c + j];
      o[j] = f2bf(t > 0.f ? t : 0.f);
    }
    *(ushortx4*)(x + e) = o;
  }
}

// out_bf16 = relu((x - mean)*inv), x fp32 [N,64]
__global__ void norm64_f32(const float* __restrict__ x, const int* __restrict__ batch_idx,
                           const float* __restrict__ mean, const float* __restrict__ inv,
                           unsigned short* __restrict__ out, int N) {
  size_t total = (size_t)N * 16;
  for (size_t i = (size_t)blockIdx.x * blockDim.x + threadIdx.x; i < total;
       i += (size_t)gridDim.x * blockDim.x) {
    size_t e = i * 4;
    int row = (int)(e >> 6);
    int c = (int)(e & 63);
    int b = batch_idx[row];
    floatx4 v = *(const floatx4*)(x + e);
    ushortx4 o;
#pragma unroll
    for (int j = 0; j < 4; ++j) {
      float t = (v[j] - mean[b * 64 + c + j]) * inv[b * 64 + c + j];
      o[j] = f2bf(t > 0.f ? t : 0.f);
    }
    *(ushortx4*)(out + e) = o;
  }
}

// sparse conv: offset k, 16 pairs/wave/iter; gather h1_bf rows, MFMA with
// W2[k] frags in registers, HW-fadd scatter into h2_pre (fp32).
#define SPC_ITERS 8
__launch_bounds__(256)
__global__ void spconv(const unsigned short* __restrict__ h1_bf,
                       const unsigned short* __restrict__ w2s,
                       const int* __restrict__ in_idx, const int* __restrict__ out_idx,
                       float* __restrict__ h2_pre, int M) {
  int k = blockIdx.y;
  int wave = threadIdx.x >> 6;
  int l = threadIdx.x & 63;
  const unsigned short* wk = w2s + (size_t)k * 4096;  // 8 frags * 512
  short8 bfrag[2][4];
#pragma unroll
  for (int s = 0; s < 2; ++s)
#pragma unroll
    for (int t = 0; t < 4; ++t)
      bfrag[s][t] = *(const short8*)(wk + ((size_t)(s * 4 + t) * 64 + l) * 8);
  const int* iidx = in_idx + (size_t)k * M;
  const int* oidx = out_idx + (size_t)k * M;
  int lane_m = l & 15, lg = l >> 4;
  for (int it = 0; it < SPC_ITERS; ++it) {
    int m0 = (blockIdx.x * 4 + wave) * (16 * SPC_ITERS) + it * 16;
    if (m0 >= M) break;
    int m = m0 + lane_m;
    bool valid = m < M;
    short8 a0 = {0, 0, 0, 0, 0, 0, 0, 0}, a1 = {0, 0, 0, 0, 0, 0, 0, 0};
    if (valid) {
      int ii = iidx[m];
      const unsigned short* arow = h1_bf + (size_t)ii * 64 + lg * 8;
      a0 = *(const short8*)(arow);
      a1 = *(const short8*)(arow + 32);
    }
    floatx4 acc[4];
#pragma unroll
    for (int t = 0; t < 4; ++t) {
      acc[t] = (floatx4){0.f, 0.f, 0.f, 0.f};
      acc[t] = __builtin_amdgcn_mfma_f32_16x16x32_bf16(a0, bfrag[0][t], acc[t], 0, 0, 0);
      acc[t] = __builtin_amdgcn_mfma_f32_16x16x32_bf16(a1, bfrag[1][t], acc[t], 0, 0, 0);
    }
    int mo = m0 + lg * 4;
    intx4 ov;
    if (mo + 3 < M) {
      ov = *(const intx4*)(oidx + mo);
    } else {
#pragma unroll
      for (int r = 0; r < 4; ++r) ov[r] = (mo + r < M) ? oidx[mo + r] : -1;
    }
#pragma unroll
    for (int reg = 0; reg < 4; ++reg) {
      int o = ov[reg];
      if (o >= 0) {
        float* dst = h2_pre + (size_t)o * 64 + lane_m;
#pragma unroll
        for (int t = 0; t < 4; ++t) unsafeAtomicAdd(dst + t * 16, acc[t][reg]);
      }
    }
  }
}

// y[N,256] (fp32, pre-norm) = h2_bf[N,64] @ W3. Block: 16 rows; wave = 64 cols.
__launch_bounds__(256)
__global__ void gemm3(const unsigned short* __restrict__ h2_bf,
                      const unsigned short* __restrict__ w3s,
                      float* __restrict__ y, int N) {
  int wave = threadIdx.x >> 6;
  int l = threadIdx.x & 63;
  int r0 = blockIdx.x * 16;
  int n0 = wave * 64;
  const unsigned short* arow = h2_bf + (size_t)(r0 + (l & 15)) * 64 + (l >> 4) * 8;
  floatx4 acc[4];
#pragma unroll
  for (int t = 0; t < 4; ++t) acc[t] = (floatx4){0.f, 0.f, 0.f, 0.f};
#pragma unroll
  for (int s = 0; s < 2; ++s) {
    short8 a = *(const short8*)(arow + s * 32);
#pragma unroll
    for (int t = 0; t < 4; ++t) {
      short8 b = *(const short8*)(w3s + ((size_t)(s * 16 + wave * 4 + t) * 64 + l) * 8);
      acc[t] = __builtin_amdgcn_mfma_f32_16x16x32_bf16(a, b, acc[t], 0, 0, 0);
    }
  }
#pragma unroll
  for (int t = 0; t < 4; ++t)
#pragma unroll
    for (int reg = 0; reg < 4; ++reg) {
      int r = r0 + (l >> 4) * 4 + reg;
      y[(size_t)r * 256 + n0 + t * 16 + (l & 15)] = acc[t][reg];
    }
}

// out = relu((y - meanC)*invC + feats), fp32 [N,256]; y aliases out (in-place,
// same-position RMW per thread -> race-free).
__global__ void final_out(const float* __restrict__ y,
                          const float* __restrict__ feats,
                          const int* __restrict__ batch_idx,
                          const float* __restrict__ mean, const float* __restrict__ inv,
                          float* __restrict__ out, int N) {
  size_t total = (size_t)N * 64;  // N*256/4
  for (size_t i = (size_t)blockIdx.x * blockDim.x + threadIdx.x; i < total;
       i += (size_t)gridDim.x * blockDim.x) {
    size_t e = i * 4;
    int row = (int)(e >> 8);
    int c = (int)(e & 255);
    int b = batch_idx[row];
    floatx4 yv = *(const floatx4*)(y + e);
    floatx4 fv = *(const floatx4*)(feats + e);
    floatx4 o;
#pragma unroll
    for (int j = 0; j < 4; ++j) {
      float t = (yv[j] - mean[b * 256 + c + j]) * inv[b * 256 + c + j] + fv[j];
      o[j] = t > 0.f ? t : 0.f;
    }
    *(floatx4*)(out + e) = o;
  }
}

extern "C" void kernel_launch(void* const* d_in, const int* in_sizes, int n_in,
                              void* d_out, int out_size, void* d_ws, size_t ws_size,
                              hipStream_t stream) {
  (void)n_in; (void)out_size; (void)ws_size;
  const float* feats = (const float*)d_in[0];
  const float* W1 = (const float*)d_in[1];
  const float* W2 = (const float*)d_in[2];
  const float* W3 = (const float*)d_in[3];
  const int* in_idx = (const int*)d_in[4];
  const int* out_idx = (const int*)d_in[5];
  const int* batch_idx = (const int*)d_in[6];
  int N = in_sizes[6];          // 200000
  int M = in_sizes[4] / 27;     // 100000

  // ---- workspace (~51.5 MB) ----
  char* base = (char*)d_ws;
  size_t off = 0;
  auto take = [&](size_t bytes) -> char* {
    char* p = base + off;
    off = (off + bytes + 255) & ~(size_t)255;
    return p;
  };
  float* zstat = (float*)take(3076 * sizeof(float));
  float* cnt = zstat;
  float* sumA = zstat + 4;   float* sqA = sumA + 256;
  float* sumB = sqA + 256;   float* sqB = sumB + 256;
  float* sumC = sqB + 256;   float* sqC = sumC + 1024;
  float* meanA = (float*)take(3072 * sizeof(float));
  float* invA = meanA + 256;
  float* meanB = invA + 256; float* invB = meanB + 256;
  float* meanC = invB + 256; float* invC = meanC + 1024;
  unsigned short* w1s = (unsigned short*)take(16384 * 2);
  unsigned short* w2s = (unsigned short*)take(110592 * 2);
  unsigned short* w3s = (unsigned short*)take(16384 * 2);
  unsigned short* h1_bf = (unsigned short*)take((size_t)N * 64 * 2);  // 25.6 MB
  unsigned short* h2_bf = (unsigned short*)take((size_t)N * 64 * 2);  // 25.6 MB

  // d_out (fp32, N*256 = 204.8 MB) doubles as scratch: h2 fp32 accumulator in
  // its first quarter (dead before gemm3 overwrites all of d_out with y).
  float* h2_pre = (float*)d_out;       // N*64 fp32 = 51.2 MB
  float* y = (float*)d_out;            // N*256 fp32, written by gemm3

  hipMemsetAsync(zstat, 0, 3076 * sizeof(float), stream);
  hipMemsetAsync(h2_pre, 0, (size_t)N * 64 * sizeof(float), stream);

  swizzle_w<<<8, 256, 0, stream>>>(W1, w1s, 256, 64, 1);
  swizzle_w<<<54, 256, 0, stream>>>(W2, w2s, 64, 64, 27);
  swizzle_w<<<8, 256, 0, stream>>>(W3, w3s, 64, 256, 1);

  gemm1<<<N / 64, 256, 0, stream>>>(feats, w1s, h1_bf, N);
  stats64_bf<<<256, 256, 0, stream>>>(h1_bf, batch_idx, sumA, sqA, cnt, N);
  finalize_stats<<<1, 256, 0, stream>>>(sumA, sqA, cnt, meanA, invA, 64);
  norm64_bf_inplace<<<1024, 256, 0, stream>>>(h1_bf, batch_idx, meanA, invA, N);

  dim3 g4((M + 511) / 512, 27);
  spconv<<<g4, 256, 0, stream>>>(h1_bf, w2s, in_idx, out_idx, h2_pre, M);
  stats64_f32<<<256, 256, 0, stream>>>(h2_pre, batch_idx, sumB, sqB, N);
  finalize_stats<<<1, 256, 0, stream>>>(sumB, sqB, cnt, meanB, invB, 64);
  norm64_f32<<<1024, 256, 0, stream>>>(h2_pre, batch_idx, meanB, invB, h2_bf, N);

  gemm3<<<N / 16, 256, 0, stream>>>(h2_bf, w3s, y, N);
  stats256_f32<<<512, 256, 0, stream>>>(y, batch_idx, sumC, sqC, N);
  finalize_stats<<<4, 256, 0, stream>>>(sumC, sqC, cnt, meanC, invC, 256);
  final_out<<<2048, 256, 0, stream>>>(y, feats, batch_idx, meanC, invC,
                                      (float*)d_out, N);
}